// Round 17
// baseline (76.452 us; speedup 1.0000x reference)
//
#include <hip/hip_runtime.h>
#include <hip/hip_bf16.h>
#include <stdint.h>

#define LOG2E 1.4426950408889634f
#define LN2   0.6931471805599453f

typedef float f32x4 __attribute__((ext_vector_type(4)));
typedef float f32x16 __attribute__((ext_vector_type(16)));
typedef short s16x8 __attribute__((ext_vector_type(8)));
typedef short s16x4 __attribute__((ext_vector_type(4)));
typedef _Float16 f16x8 __attribute__((ext_vector_type(8)));
typedef _Float16 h2x2 __attribute__((ext_vector_type(2)));
typedef uint32_t u32x4 __attribute__((ext_vector_type(4)));
typedef uint32_t u32x2 __attribute__((ext_vector_type(2)));

__device__ inline float fexp2(float x) { return __builtin_amdgcn_exp2f(x); }
__device__ inline float frcp (float x) { return __builtin_amdgcn_rcpf(x); }
__device__ inline float flog2(float x) { return __builtin_amdgcn_logf(x); }
__device__ inline float ftanh(float x) {
  float e = fexp2(x * (2.0f * LOG2E));
  return 1.0f - 2.0f * frcp(e + 1.0f);
}
__device__ inline short f2h(float x) {
  union { _Float16 f; short s; } cv; cv.f = (_Float16)x; return cv.s;
}
__device__ inline float h2f(short s) {
  union { _Float16 f; short s; } cv; cv.s = s; return (float)cv.f;
}
__device__ inline uint32_t h2bits(h2x2 v) {
  uint32_t u; __builtin_memcpy(&u, &v, 4); return u;
}
__device__ inline h2x2 bits2h(uint32_t u) {
  h2x2 v; __builtin_memcpy(&v, &u, 4); return v;
}

// ---------------------------------------------------------------------------
// Kernel M: prep.
//  blocks [0,256):   adjt1 — 16-row permuted byte-mask tiles (attn1 layout)
//  blocks [256,288): wprep fp16 hi/lo fragment planes
//  blocks [288,544): adjt0 — 32-row tiles for the 32x32-MFMA attn0:
//     adjt0[((b*32+nt32)*64+mb)*128 + l*2 + w] = FF-mask bytes of
//     adj[row = nt32*32 + (l&31)][mb*16 + 8*(l>>5) + 4w .. +3]
// ---------------------------------------------------------------------------
__global__ __launch_bounds__(256) void k_megaprep(
    const void* __restrict__ adj, uint32_t* __restrict__ adjt1,
    uint32_t* __restrict__ adjt0,
    const float* __restrict__ w0, const float* __restrict__ w1,
    short* __restrict__ wf0h, short* __restrict__ wf0l,
    short* __restrict__ wf1h, short* __restrict__ wf1l)
{
  __shared__ uint32_t smode[4];
  int blk = blockIdx.x;
  int tid = threadIdx.x;

  // dtype probe (first 512 KB — valid in both interpretations)
  const uint32_t* w32 = (const uint32_t*)adj;
  uint32_t probe = w32[(blk * 256 + tid) & 0x1FFFF];
  uint32_t any = (probe > 1u) ? 1u : 0u;
  for (int m = 1; m < 64; m <<= 1) any |= __shfl_xor(any, m, 64);
  if ((tid & 63) == 0) smode[tid >> 6] = any;
  __syncthreads();
  uint32_t bytemode = smode[0] | smode[1] | smode[2] | smode[3];

  if (blk < 256) {
    int t  = blk * 256 + tid;                     // (b, nt16, mc, c)
    int c  = t & 3;
    int mc = (t >> 2) & 31;
    int nt = (t >> 7) & 63;
    int b  = t >> 13;
    uint32_t* dst = adjt1 + (((size_t)(b * 64 + nt) * 32 + mc) * 128) + c * 32;

    if (bytemode) {
#pragma unroll 4
      for (int l15 = 0; l15 < 16; ++l15) {
        const uint8_t* src = (const uint8_t*)adj +
            ((size_t)(b * 1024 + nt * 16 + l15) * 1024 + mc * 32 + 4 * c);
        uint32_t lo = *(const uint32_t*)src;
        uint32_t hi = *(const uint32_t*)(src + 16);
        dst[2 * l15]     = lo * 0xFFu;
        dst[2 * l15 + 1] = hi * 0xFFu;
      }
    } else {
#pragma unroll 4
      for (int l15 = 0; l15 < 16; ++l15) {
        const uint32_t* src = (const uint32_t*)adj +
            ((size_t)(b * 1024 + nt * 16 + l15) * 1024 + mc * 32 + 4 * c);
        u32x4 qa = *(const u32x4*)src;
        u32x4 qb = *(const u32x4*)(src + 16);
        dst[2 * l15] = (qa[0] ? 0xFFu : 0u) | (qa[1] ? 0xFF00u : 0u) |
                       (qa[2] ? 0xFF0000u : 0u) | (qa[3] ? 0xFF000000u : 0u);
        dst[2 * l15 + 1] = (qb[0] ? 0xFFu : 0u) | (qb[1] ? 0xFF00u : 0u) |
                           (qb[2] ? 0xFF0000u : 0u) | (qb[3] ? 0xFF000000u : 0u);
      }
    }
  } else if (blk < 288) {
    int t = (blk - 256) * 256 + tid;   // 0..8191
    int layer = t >> 12;
    int r = t & 4095;
    int l = r & 63, slot = r >> 6;
    int l15 = l & 15, c = l >> 4;
    int FO  = layer ? 16 : 32;
    int FIN = layer ? 256 : 128;
    int ct  = layer ? (slot >> 3) : (slot >> 2);
    int kc  = layer ? (slot & 7)  : (slot & 3);
    int col = ct * 16 + l15;
    int h   = layer ? (col >> 4) : (col >> 5);
    int o   = col & (FO - 1);
    const float* wp = (layer ? w1 : w0) + (size_t)h * FIN * FO + o;
    short* dh = (layer ? wf1h : wf0h) + (size_t)r * 8;
    short* dl = (layer ? wf1l : wf0l) + (size_t)r * 8;
#pragma unroll
    for (int j = 0; j < 8; j++) {
      int k = kc * 32 + 4 * c + (j & 3) + ((j >> 2) << 4);
      float wv = wp[(size_t)k * FO];
      short hh = f2h(wv);
      dh[j] = hh;
      dl[j] = f2h(wv - h2f(hh));
    }
  } else {
    int idx  = blk - 288;              // 0..255 = (b, nt32)
    int b    = idx >> 5;
    int nt32 = idx & 31;
    uint32_t* dst = adjt0 + ((size_t)(b * 32 + nt32) * 64) * 128;
#pragma unroll 2
    for (int i = 0; i < 32; ++i) {
      int flat = i * 256 + tid;        // 0..8191
      int mb   = flat >> 7;
      int rem  = flat & 127;
      int l    = rem >> 1;
      int w    = rem & 1;
      int row  = nt32 * 32 + (l & 31);
      int mcol = mb * 16 + 8 * (l >> 5) + 4 * w;
      uint32_t outw;
      if (bytemode) {
        uint32_t v = *(const uint32_t*)((const uint8_t*)adj +
                     ((size_t)(b * 1024 + row) * 1024 + mcol));
        outw = v * 0xFFu;
      } else {
        const uint32_t* src = (const uint32_t*)adj +
                              ((size_t)(b * 1024 + row) * 1024 + mcol);
        u32x4 q = *(const u32x4*)src;
        outw = (q[0] ? 0xFFu : 0u) | (q[1] ? 0xFF00u : 0u) |
               (q[2] ? 0xFF0000u : 0u) | (q[3] ? 0xFF000000u : 0u);
      }
      dst[(size_t)mb * 128 + rem] = outw;
    }
  }
}

// ---------------------------------------------------------------------------
// Kernel H: h_prime = xc @ w[h]  (split-FP16 Markidis, 3 MFMAs ~ fp32 exact),
// tanh -> s; fp16 D/E tables. FUSE: embcat fused (layer 0).
// L32 epilogue (layer 0): hpb in 32x32-MFMA B arrangement
//   hpb[(((bh*64+mb)*64)+l)*8 + j] = hp[m = mb*16 + 8*(l>>5) + j][col = l&31]
// and LINEAR pair D/E tables: Dsw[bh*512 + m/2] = (2^d[m], 2^d[m+1]).
// !L32 (layer 1): original 16x16 fragment arrangement + swizzled tables.
// ---------------------------------------------------------------------------
template<int FIN, int FO, bool FUSE, bool L32>
__global__ __launch_bounds__(256) void k_hprime(
    const short* __restrict__ xcbh, const short* __restrict__ xcbl,
    const float* __restrict__ x, const int* __restrict__ verts,
    const float* __restrict__ emb,
    const short* __restrict__ wfh, const short* __restrict__ wfl,
    const float* __restrict__ a_src, const float* __restrict__ a_dst,
    short* __restrict__ hpbh, float* __restrict__ sp,
    uint32_t* __restrict__ Dsw, uint32_t* __restrict__ Esw)
{
  constexpr int CT  = FO / 16;
  constexpr int CTB = 8 * FO / 16;
  constexpr int CTW = CTB / 4;
  constexpr int KC  = FIN / 32;

  __shared__ short xsh[FUSE ? 16 : 1][FUSE ? 132 : 1];
  __shared__ short xsl[FUSE ? 16 : 1][FUSE ? 132 : 1];

  int blk = blockIdx.x;              // 512
  int b   = blk >> 6;
  int ntg = blk & 63;
  int tid = threadIdx.x;
  int w4  = tid >> 6;
  int l   = tid & 63;
  int l15 = l & 15, c = l >> 4;

  if constexpr (FUSE) {
    int t8  = tid * 8;
    int row = t8 >> 7;
    int col = t8 & 127;
    int grow = b * 1024 + ntg * 16 + row;
    f32x4 va, vb;
    if (col < 64) {
      va = *(const f32x4*)&x[(size_t)grow * 64 + col];
      vb = *(const f32x4*)&x[(size_t)grow * 64 + col + 4];
    } else {
      int vv = verts[grow];
      va = *(const f32x4*)&emb[(size_t)vv * 64 + (col - 64)];
      vb = *(const f32x4*)&emb[(size_t)vv * 64 + (col - 64) + 4];
    }
#pragma unroll
    for (int j = 0; j < 8; j++) {
      float v = (j < 4) ? va[j] : vb[j - 4];
      short hh = f2h(v);
      xsh[row][col + j] = hh;
      xsl[row][col + j] = f2h(v - h2f(hh));
    }
    __syncthreads();
  }

  int row = ntg * 16 + l15;
  const short* arowh = FUSE ? nullptr : xcbh + ((size_t)(b * 1024 + row)) * FIN;
  const short* arowl = FUSE ? nullptr : xcbl + ((size_t)(b * 1024 + row)) * FIN;

  f32x4 acc[CTW];
#pragma unroll
  for (int i = 0; i < CTW; i++) acc[i] = (f32x4){0.f, 0.f, 0.f, 0.f};

  for (int kc = 0; kc < KC; ++kc) {
    s16x4 ah0, ah1, al0, al1;
    if constexpr (FUSE) {
      ah0 = *(const s16x4*)&xsh[l15][kc * 32 + 4 * c];
      ah1 = *(const s16x4*)&xsh[l15][kc * 32 + 4 * c + 16];
      al0 = *(const s16x4*)&xsl[l15][kc * 32 + 4 * c];
      al1 = *(const s16x4*)&xsl[l15][kc * 32 + 4 * c + 16];
    } else {
      ah0 = *(const s16x4*)(arowh + kc * 32 + 4 * c);
      ah1 = *(const s16x4*)(arowh + kc * 32 + 4 * c + 16);
      al0 = *(const s16x4*)(arowl + kc * 32 + 4 * c);
      al1 = *(const s16x4*)(arowl + kc * 32 + 4 * c + 16);
    }
    union { s16x8 s; f16x8 f; } afh, afl;
#pragma unroll
    for (int j = 0; j < 4; j++) {
      afh.s[j] = ah0[j]; afh.s[4 + j] = ah1[j];
      afl.s[j] = al0[j]; afl.s[4 + j] = al1[j];
    }
#pragma unroll
    for (int i = 0; i < CTW; i++) {
      int ct = w4 * CTW + i;
      union { s16x8 s; f16x8 f; } bfh, bfl;
      bfh.s = *(const s16x8*)(wfh + ((size_t)(ct * KC + kc) * 64 + l) * 8);
      bfl.s = *(const s16x8*)(wfl + ((size_t)(ct * KC + kc) * 64 + l) * 8);
      acc[i] = __builtin_amdgcn_mfma_f32_16x16x32_f16(afh.f, bfh.f, acc[i], 0, 0, 0);
      acc[i] = __builtin_amdgcn_mfma_f32_16x16x32_f16(afl.f, bfh.f, acc[i], 0, 0, 0);
      acc[i] = __builtin_amdgcn_mfma_f32_16x16x32_f16(afh.f, bfl.f, acc[i], 0, 0, 0);
    }
  }

  float s_acc[CTW][4];
  float d_acc[CTW][4];
#pragma unroll
  for (int i = 0; i < CTW; i++) {
    int ct  = w4 * CTW + i;
    int col = ct * 16 + l15;
    int h = col / FO, o = col % FO;
    float asv = a_src[h * FO + o];
    float adv = a_dst[h * FO + o];
    s16x4 hbh;
#pragma unroll
    for (int r = 0; r < 4; r++) {
      float hp = acc[i][r];
      hbh[r] = f2h(hp);
      float t = ftanh(hp);
      s_acc[i][r] = t * asv;
      d_acc[i][r] = t * adv;
    }
    int bh  = b * 8 + h;
    if constexpr (L32) {
      // m = ntg*16 + 4c + r  -> elem j = m&7 = 4*(c&1)+r, half = c>>1, lane = half*32 + o
      size_t eidx = (((size_t)(bh * 64 + ntg) * 64) + (c >> 1) * 32 + o) * 8 + 4 * (c & 1);
      *(s16x4*)(hpbh + eidx) = hbh;
    } else {
      int ctl = o >> 4;
      size_t off = ((((size_t)(bh * 32 + (ntg >> 1))) * CT + ctl) * 64 + l) * 16 + (size_t)(ntg & 1) * 8;
      *(s16x4*)((char*)hpbh + off) = hbh;
    }
  }

  constexpr int HW = (CTW * 16) / FO;   // heads per wave (=2)
#pragma unroll
  for (int hh = 0; hh < HW; ++hh) {
    float sred[4], dred[4];
#pragma unroll
    for (int r = 0; r < 4; r++) {
      float sv = 0.f, dv = 0.f;
#pragma unroll
      for (int i = hh * CT; i < (hh + 1) * CT; ++i) { sv += s_acc[i][r]; dv += d_acc[i][r]; }
      for (int m = 1; m < 16; m <<= 1) {
        sv += __shfl_xor(sv, m, 64);
        dv += __shfl_xor(dv, m, 64);
      }
      sred[r] = sv * LOG2E;
      dred[r] = dv * LOG2E;
    }
    if (l15 == 0) {
      int ct0 = w4 * CTW + hh * CT;
      int h   = (ct0 * 16) / FO;
      int bh  = b * 8 + h;
      f32x4 sv4; sv4[0] = sred[0]; sv4[1] = sred[1]; sv4[2] = sred[2]; sv4[3] = sred[3];
      *(f32x4*)&sp[bh * 1024 + ntg * 16 + 4 * c] = sv4;
      h2x2 Da; Da[0] = (_Float16)fexp2(dred[0]); Da[1] = (_Float16)fexp2(dred[1]);
      h2x2 Db; Db[0] = (_Float16)fexp2(dred[2]); Db[1] = (_Float16)fexp2(dred[3]);
      h2x2 Ea; Ea[0] = (_Float16)fexp2(0.2f * dred[0]); Ea[1] = (_Float16)fexp2(0.2f * dred[1]);
      h2x2 Eb; Eb[0] = (_Float16)fexp2(0.2f * dred[2]); Eb[1] = (_Float16)fexp2(0.2f * dred[3]);
      u32x2 dw; dw[0] = h2bits(Da); dw[1] = h2bits(Db);
      u32x2 ew; ew[0] = h2bits(Ea); ew[1] = h2bits(Eb);
      int s1 = L32 ? (ntg * 8 + 2 * c)                         // linear pairs
                   : ((ntg >> 1) * 16 + 4 * c + 2 * (ntg & 1)); // 16x16 swizzle
      *(u32x2*)&Dsw[bh * 512 + s1] = dw;
      *(u32x2*)&Esw[bh * 512 + s1] = ew;
    }
  }
}

// ---------------------------------------------------------------------------
// Kernel A0 (layer 0): 32x32x16 f16 MFMA attention.
//  wave = (r32 = wid>>2, q = wid&3): 32 rows x 256 m; hp redundancy 2x (was 4x).
//  psum via packed fp16 adds (no ones-MFMA). Output D: col=l&31,
//  row=(reg&3)+8*(reg>>2)+4*(l>>5) [guide-verified].
// ---------------------------------------------------------------------------
__global__ __launch_bounds__(512, 8) void k_attn0(
    const float* __restrict__ sp, const uint32_t* __restrict__ Dsw,
    const uint32_t* __restrict__ Esw,
    const short* __restrict__ hpbh,
    const uint32_t* __restrict__ adjt0,
    const float* __restrict__ bias,
    short* __restrict__ outh, short* __restrict__ outl)
{
  __shared__ uint32_t Dl[512];
  __shared__ uint32_t El[512];
  __shared__ float redm[8];
  __shared__ float racc[2][3][16][64];   // 24 KB: q=1..3 partial acc
  __shared__ float qsum[2][4][32];
  __shared__ float rsum[2][32];

  int i0   = blockIdx.x;          // 1024
  int xcd  = i0 & 7, slot = i0 >> 3;
  int bh   = xcd * 8 + (slot >> 4);
  int rb   = (slot & 15) * 64;
  int b    = bh >> 3;
  int tid  = threadIdx.x;
  int wid  = tid >> 6;
  int r32  = wid >> 2;            // 0..1 row group
  int q    = wid & 3;             // 0..3 m quarter
  int l    = tid & 63;
  int l31  = l & 31, hh = l >> 5;

  uint32_t dw = Dsw[bh * 512 + tid];
  Dl[tid] = dw;
  El[tid] = Esw[bh * 512 + tid];
  h2x2 dv2 = bits2h(dw);
  float mv = fmaxf((float)dv2[0], (float)dv2[1]);
  for (int m = 1; m < 64; m <<= 1) mv = fmaxf(mv, __shfl_xor(mv, m, 64));
  if (l == 0) redm[wid] = mv;
  __syncthreads();
  float Dmax = redm[0];
#pragma unroll
  for (int i = 1; i < 8; i++) Dmax = fmaxf(Dmax, redm[i]);
  float maxd = flog2(Dmax);

  int rowbase = rb + r32 * 32;
  float svn = sp[bh * 1024 + rowbase + l31];
  float su  = svn + maxd;
  float ub  = fmaxf(su, 0.2f * su);
  float cAf = fexp2(svn - ub + 8.0f);          // x256
  float cBf = fexp2(0.2f * svn - ub + 8.0f);
  h2x2 cA2; cA2[0] = (_Float16)cAf; cA2[1] = (_Float16)cAf;
  h2x2 cB2; cB2[0] = (_Float16)cBf; cB2[1] = (_Float16)cBf;

  int nt32 = (rowbase >> 5);      // 0..31 within b
  const uint32_t* atile = adjt0 + ((size_t)(b * 32 + nt32) * 64) * 128 + l * 2;
  const u32x4* hpf = (const u32x4*)hpbh + ((size_t)(bh * 64) * 64 + l);

  f32x16 acc = {};
  float psum = 0.f;

  const int mbBeg = q * 16;
  u32x2 nam = *(const u32x2*)(atile + (size_t)mbBeg * 128);
  u32x4 nb  = hpf[(size_t)mbBeg * 64];

#pragma unroll
  for (int t = 0; t < 16; ++t) {
    int mb = mbBeg + t;
    u32x2 am = nam;
    union { u32x4 w; f16x8 f; } cb;
    cb.w = nb;
    if (t < 15) {
      nam = *(const u32x2*)(atile + (size_t)(mb + 1) * 128);
      nb  = hpf[(size_t)(mb + 1) * 64];
    }

    u32x4 dq = *(const u32x4*)&Dl[mb * 8 + 4 * hh];
    u32x4 eq = *(const u32x4*)&El[mb * 8 + 4 * hh];

    union { u32x4 w; f16x8 f; } pu;
#pragma unroll
    for (int tt = 0; tt < 4; ++tt) {
      h2x2 p2 = __builtin_elementwise_max(cA2 * bits2h(dq[tt]), cB2 * bits2h(eq[tt]));
      uint32_t msk = __builtin_amdgcn_perm(0u, am[tt >> 1],
                                           (tt & 1) ? 0x03030202u : 0x01010000u);
      pu.w[tt] = h2bits(p2) & msk;
    }

    // lane-local row-partial sum (row = l31 fixed for this lane)
    h2x2 s01 = bits2h(pu.w[0]) + bits2h(pu.w[1]);
    h2x2 s23 = bits2h(pu.w[2]) + bits2h(pu.w[3]);
    h2x2 ss  = s01 + s23;
    psum += (float)ss[0] + (float)ss[1];

    acc = __builtin_amdgcn_mfma_f32_32x32x16_f16(pu.f, cb.f, acc, 0, 0, 0);
  }

  // row sums: combine the two lane-halves (same row, different k-half)
  psum += __shfl_xor(psum, 32, 64);

  if (q != 0) {
#pragma unroll
    for (int r = 0; r < 16; r++) racc[r32][q - 1][r][l] = acc[r];
  }
  if (l < 32) qsum[r32][q][l31] = psum;
  __syncthreads();
  if (q == 0 && l < 32)
    rsum[r32][l31] = qsum[r32][0][l31] + qsum[r32][1][l31] +
                     qsum[r32][2][l31] + qsum[r32][3][l31];
  __syncthreads();

  if (q == 0) {
    int h = bh & 7;
    float bv = bias[l31];          // col = l31, FO = 32
#pragma unroll
    for (int r = 0; r < 16; r++) {
      float v = acc[r] + racc[r32][0][r][l] + racc[r32][1][r][l] + racc[r32][2][r][l];
      int rown = (r & 3) + 8 * (r >> 2) + 4 * hh;
      v = v * frcp(rsum[r32][rown]) + bv;
      v = v > 0.f ? v : fexp2(v * LOG2E) - 1.f;   // elu
      size_t idx = ((size_t)(b * 1024 + rowbase + rown)) * 256 + h * 32 + l31;
      short vh = f2h(v);
      outh[idx] = vh;
      outl[idx] = f2h(v - h2f(vh));
    }
  }
}

// ---------------------------------------------------------------------------
// Kernel A1 (layer 1): 16x16 path, unchanged from round 13/16 (proven).
// ---------------------------------------------------------------------------
template<int CT>
__global__ __launch_bounds__(512, 8) void k_attn1(
    const float* __restrict__ sp, const uint32_t* __restrict__ Dsw,
    const uint32_t* __restrict__ Esw,
    const short* __restrict__ hpbh,
    const uint32_t* __restrict__ adjt,
    float* __restrict__ outp)
{
  __shared__ uint32_t Dl[512];
  __shared__ uint32_t El[512];
  __shared__ float redm[8];
  __shared__ float racc[4][(CT + 1) * 4][64];

  int i0   = blockIdx.x;
  int xcd  = i0 & 7, slot = i0 >> 3;
  int bh   = xcd * 8 + (slot >> 4);
  int rb   = (slot & 15) * 64;
  int b    = bh >> 3;
  int tid  = threadIdx.x;
  int wid  = tid >> 6;
  int r16  = wid >> 1;
  int half = wid & 1;
  int l = tid & 63, l15 = l & 15, c = l >> 4;

  uint32_t dw = Dsw[bh * 512 + tid];
  Dl[tid] = dw;
  El[tid] = Esw[bh * 512 + tid];
  h2x2 dv2 = bits2h(dw);
  float mv = fmaxf((float)dv2[0], (float)dv2[1]);
  for (int m = 1; m < 64; m <<= 1) mv = fmaxf(mv, __shfl_xor(mv, m, 64));
  if (l == 0) redm[wid] = mv;
  __syncthreads();
  float Dmax = redm[0];
#pragma unroll
  for (int i = 1; i < 8; i++) Dmax = fmaxf(Dmax, redm[i]);
  float maxd = flog2(Dmax);

  int n = rb + r16 * 16 + l15;
  float svn = sp[bh * 1024 + n];
  float su  = svn + maxd;
  float ub  = fmaxf(su, 0.2f * su);
  float cAf = fexp2(svn - ub + 8.0f);
  float cBf = fexp2(0.2f * svn - ub + 8.0f);
  h2x2 cA2; cA2[0] = (_Float16)cAf; cA2[1] = (_Float16)cAf;
  h2x2 cB2; cB2[0] = (_Float16)cBf; cB2[1] = (_Float16)cBf;
  const short* hpbase = hpbh + (size_t)bh * 32 * CT * 512;
  const uint32_t* atile = adjt + ((size_t)(b * 64 + (rb >> 4) + r16) * 32) * 128 + l * 2;

  f32x4 acc[CT];
#pragma unroll
  for (int i = 0; i < CT; i++) acc[i] = (f32x4){0.f, 0.f, 0.f, 0.f};
  f32x4 accp = (f32x4){0.f, 0.f, 0.f, 0.f};
  union { s16x8 s; f16x8 f; } ones;
#pragma unroll
  for (int j = 0; j < 8; j++) ones.s[j] = (short)0x3C00;

  const int mcBeg = half * 16;
  u32x2 nam = *(const u32x2*)(atile + (size_t)mcBeg * 128);
  s16x8 nb[CT];
#pragma unroll
  for (int i = 0; i < CT; i++)
    nb[i] = *(const s16x8*)(hpbase + ((size_t)(mcBeg * CT + i) * 64 + l) * 8);
  u32x4 ndq = *(const u32x4*)&Dl[mcBeg * 16 + 4 * c];
  u32x4 neq = *(const u32x4*)&El[mcBeg * 16 + 4 * c];

#pragma unroll
  for (int t = 0; t < 16; ++t) {
    int mc = mcBeg + t;
    u32x2 am = nam;
    u32x4 dq = ndq, eq = neq;
    union { s16x8 s; f16x8 f; } cb[CT];
#pragma unroll
    for (int i = 0; i < CT; i++) cb[i].s = nb[i];
    if (t < 15) {
      int mcn = mc + 1;
      nam = *(const u32x2*)(atile + (size_t)mcn * 128);
#pragma unroll
      for (int i = 0; i < CT; i++)
        nb[i] = *(const s16x8*)(hpbase + ((size_t)(mcn * CT + i) * 64 + l) * 8);
      ndq = *(const u32x4*)&Dl[mcn * 16 + 4 * c];
      neq = *(const u32x4*)&El[mcn * 16 + 4 * c];
    }

    union { u32x4 w; s16x8 s; f16x8 f; } pu;
#pragma unroll
    for (int tt = 0; tt < 4; ++tt) {
      h2x2 p2 = __builtin_elementwise_max(cA2 * bits2h(dq[tt]), cB2 * bits2h(eq[tt]));
      uint32_t msk = __builtin_amdgcn_perm(0u, am[tt >> 1],
                                           (tt & 1) ? 0x03030202u : 0x01010000u);
      pu.w[tt] = h2bits(p2) & msk;
    }

#pragma unroll
    for (int i = 0; i < CT; i++)
      acc[i] = __builtin_amdgcn_mfma_f32_16x16x32_f16(pu.f, cb[i].f, acc[i], 0, 0, 0);
    accp = __builtin_amdgcn_mfma_f32_16x16x32_f16(pu.f, ones.f, accp, 0, 0, 0);
  }

  if (half == 1) {
#pragma unroll
    for (int i = 0; i < CT; i++)
#pragma unroll
      for (int r = 0; r < 4; r++) racc[r16][i * 4 + r][l] = acc[i][r];
#pragma unroll
    for (int r = 0; r < 4; r++) racc[r16][CT * 4 + r][l] = accp[r];
  }
  __syncthreads();
  if (half == 0) {
#pragma unroll
    for (int i = 0; i < CT; i++)
#pragma unroll
      for (int r = 0; r < 4; r++) acc[i][r] += racc[r16][i * 4 + r][l];
#pragma unroll
    for (int r = 0; r < 4; r++) {
      float rs  = accp[r] + racc[r16][CT * 4 + r][l];
      float inv = frcp(rs);
      int rown  = rb + r16 * 16 + 4 * c + r;
#pragma unroll
      for (int i = 0; i < CT; i++) {
        float v = acc[i][r] * inv;
        int col = i * 16 + l15;
        int h   = bh & 7;
        outp[(((size_t)(b * 8 + h)) * 1024 + rown) * 16 + col] = v;
      }
    }
  }
}

// ---------------------------------------------------------------------------
// Kernel F: mean over heads + bias + log_softmax(16)
// ---------------------------------------------------------------------------
__global__ __launch_bounds__(256) void k_final(
    const float* __restrict__ out1, const float* __restrict__ b1,
    float* __restrict__ out)
{
  int idx = blockIdx.x * 256 + threadIdx.x;
  if (idx >= 8192) return;
  int b = idx >> 10, n = idx & 1023;
  float v[16];
#pragma unroll
  for (int o = 0; o < 16; o++) v[o] = 0.f;
  for (int h = 0; h < 8; h++) {
    const float* p = out1 + (((size_t)(b * 8 + h)) * 1024 + n) * 16;
#pragma unroll
    for (int o = 0; o < 16; o++) v[o] += p[o];
  }
  float mx = -1e30f;
#pragma unroll
  for (int o = 0; o < 16; o++) {
    v[o] = v[o] * 0.125f + b1[o];
    mx = fmaxf(mx, v[o]);
  }
  float s = 0.f;
#pragma unroll
  for (int o = 0; o < 16; o++) s += fexp2((v[o] - mx) * LOG2E);
  float lse = flog2(s) * LN2;
#pragma unroll
  for (int o = 0; o < 16; o++) out[(size_t)idx * 16 + o] = v[o] - mx - lse;
}

// ---------------------------------------------------------------------------
extern "C" void kernel_launch(void* const* d_in, const int* in_sizes, int n_in,
                              void* d_out, int out_size, void* d_ws, size_t ws_size,
                              hipStream_t stream) {
  const float*   x     = (const float*)d_in[0];
  const int*     verts = (const int*)d_in[1];
  const void*    adj   = (const void*)d_in[2];   // int32 or uint8 — auto-detected
  const float*   emb   = (const float*)d_in[3];
  const float*   w0    = (const float*)d_in[4];
  const float*   as0   = (const float*)d_in[5];
  const float*   ad0   = (const float*)d_in[6];
  const float*   b0    = (const float*)d_in[7];
  const float*   w1    = (const float*)d_in[8];
  const float*   as1   = (const float*)d_in[9];
  const float*   ad1   = (const float*)d_in[10];
  const float*   b1    = (const float*)d_in[11];

  char* ws = (char*)d_ws;
  const size_t MB = 1ull << 20;
  const size_t KB = 1024;
  short* hpb0h = (short*)(ws);                         // 4 MB (dead after attn0)
  float* out1  = (float*)(ws);                         // 4 MB (aliases hpb0h)
  short* x1h   = (short*)(ws + 4 * MB);                // 4 MB
  short* x1l   = (short*)(ws + 8 * MB);                // 4 MB
  short* hpb1h = (short*)(ws + 12 * MB);               // 2 MB
  uint32_t* adjt1 = (uint32_t*)(ws + 14 * MB);         // 8 MB (16-row tiles)
  uint32_t* adjt0 = (uint32_t*)(ws + 22 * MB);         // 8 MB (32-row tiles)
  float* s0    = (float*)(ws + 30 * MB);               // 256 KB
  float* s1    = (float*)(ws + 30 * MB + 256 * KB);    // 256 KB
  short* wf0h  = (short*)(ws + 30 * MB + 512 * KB);    // 64 KB each
  short* wf0l  = (short*)(ws + 30 * MB + 576 * KB);
  short* wf1h  = (short*)(ws + 30 * MB + 640 * KB);
  short* wf1l  = (short*)(ws + 30 * MB + 704 * KB);
  uint32_t* Dsw0 = (uint32_t*)(ws + 30 * MB + 768 * KB);   // 128 KB each
  uint32_t* Esw0 = (uint32_t*)(ws + 30 * MB + 896 * KB);
  uint32_t* Dsw1 = (uint32_t*)(ws + 31 * MB);
  uint32_t* Esw1 = (uint32_t*)(ws + 31 * MB + 128 * KB);
  float* out   = (float*)d_out;

  k_megaprep<<<544, 256, 0, stream>>>(adj, adjt1, adjt0, w0, w1,
                                      wf0h, wf0l, wf1h, wf1l);
  k_hprime<128, 32, true, true><<<512, 256, 0, stream>>>(
      nullptr, nullptr, x, verts, emb, wf0h, wf0l, as0, ad0,
      hpb0h, s0, Dsw0, Esw0);
  k_attn0<<<1024, 512, 0, stream>>>(s0, Dsw0, Esw0, hpb0h, adjt0, b0, x1h, x1l);
  k_hprime<256, 16, false, false><<<512, 256, 0, stream>>>(
      x1h, x1l, nullptr, nullptr, nullptr, wf1h, wf1l, as1, ad1,
      hpb1h, s1, Dsw1, Esw1);
  k_attn1<1><<<1024, 512, 0, stream>>>(s1, Dsw1, Esw1, hpb1h, adjt1, out1);
  k_final<<<32, 256, 0, stream>>>(out1, b1, out);
}

// Round 18
// 66.747 us; speedup vs baseline: 1.1454x; 1.1454x over previous
//
#include <hip/hip_runtime.h>
#include <hip/hip_bf16.h>
#include <stdint.h>

#define LOG2E 1.4426950408889634f
#define LN2   0.6931471805599453f

typedef float f32x4 __attribute__((ext_vector_type(4)));
typedef short s16x8 __attribute__((ext_vector_type(8)));
typedef short s16x4 __attribute__((ext_vector_type(4)));
typedef _Float16 f16x8 __attribute__((ext_vector_type(8)));
typedef _Float16 h2x2 __attribute__((ext_vector_type(2)));
typedef uint32_t u32x4 __attribute__((ext_vector_type(4)));
typedef uint32_t u32x2 __attribute__((ext_vector_type(2)));

__device__ inline float fexp2(float x) { return __builtin_amdgcn_exp2f(x); }
__device__ inline float frcp (float x) { return __builtin_amdgcn_rcpf(x); }
__device__ inline float flog2(float x) { return __builtin_amdgcn_logf(x); }
__device__ inline float ftanh(float x) {
  float e = fexp2(x * (2.0f * LOG2E));
  return 1.0f - 2.0f * frcp(e + 1.0f);
}
__device__ inline short f2h(float x) {
  union { _Float16 f; short s; } cv; cv.f = (_Float16)x; return cv.s;
}
__device__ inline float h2f(short s) {
  union { _Float16 f; short s; } cv; cv.s = s; return (float)cv.f;
}
__device__ inline uint32_t h2bits(h2x2 v) {
  uint32_t u; __builtin_memcpy(&u, &v, 4); return u;
}
__device__ inline h2x2 bits2h(uint32_t u) {
  h2x2 v; __builtin_memcpy(&v, &u, 4); return v;
}

// ---------------------------------------------------------------------------
// Kernel M: prep — adjperm (blocks 0..255) + wprep fp16 hi/lo (256..287).
// (embcat fused into k_hprime<...,true> — xcb round-trip eliminated.)
// ---------------------------------------------------------------------------
__global__ __launch_bounds__(256) void k_megaprep(
    const void* __restrict__ adj, uint32_t* __restrict__ adjt,
    const float* __restrict__ w0, const float* __restrict__ w1,
    short* __restrict__ wf0h, short* __restrict__ wf0l,
    short* __restrict__ wf1h, short* __restrict__ wf1l)
{
  __shared__ uint32_t smode[4];
  int blk = blockIdx.x;
  int tid = threadIdx.x;

  if (blk < 256) {
    const uint32_t* w32 = (const uint32_t*)adj;
    uint32_t probe = w32[blk * 256 + tid];        // <256 KB: safe both modes
    uint32_t any = (probe > 1u) ? 1u : 0u;
    for (int m = 1; m < 64; m <<= 1) any |= __shfl_xor(any, m, 64);
    if ((tid & 63) == 0) smode[tid >> 6] = any;
    __syncthreads();
    uint32_t bytemode = smode[0] | smode[1] | smode[2] | smode[3];

    int t  = blk * 256 + tid;                     // (b, nt16, mc, c)
    int c  = t & 3;
    int mc = (t >> 2) & 31;
    int nt = (t >> 7) & 63;
    int b  = t >> 13;
    uint32_t* dst = adjt + (((size_t)(b * 64 + nt) * 32 + mc) * 128) + c * 32;

    if (bytemode) {
#pragma unroll 4
      for (int l15 = 0; l15 < 16; ++l15) {
        const uint8_t* src = (const uint8_t*)adj +
            ((size_t)(b * 1024 + nt * 16 + l15) * 1024 + mc * 32 + 4 * c);
        uint32_t lo = *(const uint32_t*)src;
        uint32_t hi = *(const uint32_t*)(src + 16);
        dst[2 * l15]     = lo * 0xFFu;
        dst[2 * l15 + 1] = hi * 0xFFu;
      }
    } else {
#pragma unroll 4
      for (int l15 = 0; l15 < 16; ++l15) {
        const uint32_t* src = (const uint32_t*)adj +
            ((size_t)(b * 1024 + nt * 16 + l15) * 1024 + mc * 32 + 4 * c);
        u32x4 qa = *(const u32x4*)src;
        u32x4 qb = *(const u32x4*)(src + 16);
        dst[2 * l15] = (qa[0] ? 0xFFu : 0u) | (qa[1] ? 0xFF00u : 0u) |
                       (qa[2] ? 0xFF0000u : 0u) | (qa[3] ? 0xFF000000u : 0u);
        dst[2 * l15 + 1] = (qb[0] ? 0xFFu : 0u) | (qb[1] ? 0xFF00u : 0u) |
                           (qb[2] ? 0xFF0000u : 0u) | (qb[3] ? 0xFF000000u : 0u);
      }
    }
  } else {
    int t = (blk - 256) * 256 + tid;   // 0..8191
    int layer = t >> 12;
    int r = t & 4095;
    int l = r & 63, slot = r >> 6;
    int l15 = l & 15, c = l >> 4;
    int FO  = layer ? 16 : 32;
    int FIN = layer ? 256 : 128;
    int ct  = layer ? (slot >> 3) : (slot >> 2);
    int kc  = layer ? (slot & 7)  : (slot & 3);
    int col = ct * 16 + l15;
    int h   = layer ? (col >> 4) : (col >> 5);
    int o   = col & (FO - 1);
    const float* wp = (layer ? w1 : w0) + (size_t)h * FIN * FO + o;
    short* dh = (layer ? wf1h : wf0h) + (size_t)r * 8;
    short* dl = (layer ? wf1l : wf0l) + (size_t)r * 8;
#pragma unroll
    for (int j = 0; j < 8; j++) {
      int k = kc * 32 + 4 * c + (j & 3) + ((j >> 2) << 4);
      float wv = wp[(size_t)k * FO];
      short hh = f2h(wv);
      dh[j] = hh;
      dl[j] = f2h(wv - h2f(hh));
    }
  }
}

// ---------------------------------------------------------------------------
// Kernel H: h_prime = xc @ w[h]  (split-FP16 Markidis, 3 MFMAs ~ fp32 exact),
// tanh -> s; writes lane-swizzled fp16 D/E tables (no atomics).
// FUSE=true (layer 0): builds its 16-row x||emb tile in LDS (embcat fused).
// hpb stored FP16, FRAGMENT-ARRANGED: [bh][mc(32)][ctl(CT)][lane(64)][8 f16]
// ---------------------------------------------------------------------------
template<int FIN, int FO, bool FUSE>
__global__ __launch_bounds__(256) void k_hprime(
    const short* __restrict__ xcbh, const short* __restrict__ xcbl,
    const float* __restrict__ x, const int* __restrict__ verts,
    const float* __restrict__ emb,
    const short* __restrict__ wfh, const short* __restrict__ wfl,
    const float* __restrict__ a_src, const float* __restrict__ a_dst,
    short* __restrict__ hpbh, float* __restrict__ sp,
    uint32_t* __restrict__ Dsw, uint32_t* __restrict__ Esw)
{
  constexpr int CT  = FO / 16;
  constexpr int CTB = 8 * FO / 16;
  constexpr int CTW = CTB / 4;
  constexpr int KC  = FIN / 32;

  __shared__ short xsh[FUSE ? 16 : 1][FUSE ? 132 : 1];
  __shared__ short xsl[FUSE ? 16 : 1][FUSE ? 132 : 1];

  int blk = blockIdx.x;              // 512
  int b   = blk >> 6;
  int ntg = blk & 63;
  int tid = threadIdx.x;
  int w4  = tid >> 6;
  int l   = tid & 63;
  int l15 = l & 15, c = l >> 4;

  if constexpr (FUSE) {
    // ---- fused embcat: build 16x128 fp16 hi/lo tile for this block's rows ----
    int t8  = tid * 8;
    int row = t8 >> 7;          // 0..15
    int col = t8 & 127;         // multiple of 8
    int grow = b * 1024 + ntg * 16 + row;
    f32x4 va, vb;
    if (col < 64) {
      va = *(const f32x4*)&x[(size_t)grow * 64 + col];
      vb = *(const f32x4*)&x[(size_t)grow * 64 + col + 4];
    } else {
      int vv = verts[grow];
      va = *(const f32x4*)&emb[(size_t)vv * 64 + (col - 64)];
      vb = *(const f32x4*)&emb[(size_t)vv * 64 + (col - 64) + 4];
    }
#pragma unroll
    for (int j = 0; j < 8; j++) {
      float v = (j < 4) ? va[j] : vb[j - 4];
      short hh = f2h(v);
      xsh[row][col + j] = hh;
      xsl[row][col + j] = f2h(v - h2f(hh));
    }
    __syncthreads();
  }

  int row = ntg * 16 + l15;
  const short* arowh = FUSE ? nullptr : xcbh + ((size_t)(b * 1024 + row)) * FIN;
  const short* arowl = FUSE ? nullptr : xcbl + ((size_t)(b * 1024 + row)) * FIN;

  f32x4 acc[CTW];
#pragma unroll
  for (int i = 0; i < CTW; i++) acc[i] = (f32x4){0.f, 0.f, 0.f, 0.f};

  for (int kc = 0; kc < KC; ++kc) {
    s16x4 ah0, ah1, al0, al1;
    if constexpr (FUSE) {
      ah0 = *(const s16x4*)&xsh[l15][kc * 32 + 4 * c];
      ah1 = *(const s16x4*)&xsh[l15][kc * 32 + 4 * c + 16];
      al0 = *(const s16x4*)&xsl[l15][kc * 32 + 4 * c];
      al1 = *(const s16x4*)&xsl[l15][kc * 32 + 4 * c + 16];
    } else {
      ah0 = *(const s16x4*)(arowh + kc * 32 + 4 * c);
      ah1 = *(const s16x4*)(arowh + kc * 32 + 4 * c + 16);
      al0 = *(const s16x4*)(arowl + kc * 32 + 4 * c);
      al1 = *(const s16x4*)(arowl + kc * 32 + 4 * c + 16);
    }
    union { s16x8 s; f16x8 f; } afh, afl;
#pragma unroll
    for (int j = 0; j < 4; j++) {
      afh.s[j] = ah0[j]; afh.s[4 + j] = ah1[j];
      afl.s[j] = al0[j]; afl.s[4 + j] = al1[j];
    }
#pragma unroll
    for (int i = 0; i < CTW; i++) {
      int ct = w4 * CTW + i;
      union { s16x8 s; f16x8 f; } bfh, bfl;
      bfh.s = *(const s16x8*)(wfh + ((size_t)(ct * KC + kc) * 64 + l) * 8);
      bfl.s = *(const s16x8*)(wfl + ((size_t)(ct * KC + kc) * 64 + l) * 8);
      acc[i] = __builtin_amdgcn_mfma_f32_16x16x32_f16(afh.f, bfh.f, acc[i], 0, 0, 0);
      acc[i] = __builtin_amdgcn_mfma_f32_16x16x32_f16(afl.f, bfh.f, acc[i], 0, 0, 0);
      acc[i] = __builtin_amdgcn_mfma_f32_16x16x32_f16(afh.f, bfl.f, acc[i], 0, 0, 0);
    }
  }

  float s_acc[CTW][4];
  float d_acc[CTW][4];
#pragma unroll
  for (int i = 0; i < CTW; i++) {
    int ct  = w4 * CTW + i;
    int col = ct * 16 + l15;
    int h = col / FO, o = col % FO;
    float asv = a_src[h * FO + o];
    float adv = a_dst[h * FO + o];
    s16x4 hbh;
#pragma unroll
    for (int r = 0; r < 4; r++) {
      float hp = acc[i][r];
      hbh[r] = f2h(hp);
      float t = ftanh(hp);
      s_acc[i][r] = t * asv;
      d_acc[i][r] = t * adv;
    }
    int bh  = b * 8 + h;
    int ctl = o >> 4;
    size_t off = ((((size_t)(bh * 32 + (ntg >> 1))) * CT + ctl) * 64 + l) * 16 + (size_t)(ntg & 1) * 8;
    *(s16x4*)((char*)hpbh + off) = hbh;
  }

  constexpr int HW = (CTW * 16) / FO;   // heads per wave (=2)
#pragma unroll
  for (int hh = 0; hh < HW; ++hh) {
    float sred[4], dred[4];
#pragma unroll
    for (int r = 0; r < 4; r++) {
      float sv = 0.f, dv = 0.f;
#pragma unroll
      for (int i = hh * CT; i < (hh + 1) * CT; ++i) { sv += s_acc[i][r]; dv += d_acc[i][r]; }
      for (int m = 1; m < 16; m <<= 1) {
        sv += __shfl_xor(sv, m, 64);
        dv += __shfl_xor(dv, m, 64);
      }
      sred[r] = sv * LOG2E;
      dred[r] = dv * LOG2E;
    }
    if (l15 == 0) {
      int ct0 = w4 * CTW + hh * CT;
      int h   = (ct0 * 16) / FO;
      int bh  = b * 8 + h;
      f32x4 sv4; sv4[0] = sred[0]; sv4[1] = sred[1]; sv4[2] = sred[2]; sv4[3] = sred[3];
      *(f32x4*)&sp[bh * 1024 + ntg * 16 + 4 * c] = sv4;
      int s1 = (ntg >> 1) * 16 + 4 * c + 2 * (ntg & 1);
      h2x2 Da; Da[0] = (_Float16)fexp2(dred[0]); Da[1] = (_Float16)fexp2(dred[1]);
      h2x2 Db; Db[0] = (_Float16)fexp2(dred[2]); Db[1] = (_Float16)fexp2(dred[3]);
      h2x2 Ea; Ea[0] = (_Float16)fexp2(0.2f * dred[0]); Ea[1] = (_Float16)fexp2(0.2f * dred[1]);
      h2x2 Eb; Eb[0] = (_Float16)fexp2(0.2f * dred[2]); Eb[1] = (_Float16)fexp2(0.2f * dred[3]);
      u32x2 dw; dw[0] = h2bits(Da); dw[1] = h2bits(Db);
      u32x2 ew; ew[0] = h2bits(Ea); ew[1] = h2bits(Eb);
      *(u32x2*)&Dsw[bh * 512 + s1] = dw;
      *(u32x2*)&Esw[bh * 512 + s1] = ew;
    }
  }
}

// ---------------------------------------------------------------------------
// Kernel A: masked softmax(leaky(s+d)) @ h_prime — packed-fp16 score path
// (round-13 structure: direct global hpb loads, dist-1 staging, unrolled).
// ---------------------------------------------------------------------------
template<int CT, bool IS_L0>
__global__ __launch_bounds__(512, 8) void k_attn(
    const float* __restrict__ sp, const uint32_t* __restrict__ Dsw,
    const uint32_t* __restrict__ Esw,
    const short* __restrict__ hpbh,
    const uint32_t* __restrict__ adjt,
    const float* __restrict__ bias,
    void* __restrict__ outh, void* __restrict__ outl)
{
  __shared__ uint32_t Dl[512];
  __shared__ uint32_t El[512];
  __shared__ float redm[8];
  __shared__ float racc[4][(CT + 1) * 4][64];

  int i0   = blockIdx.x;          // 1024
  int xcd  = i0 & 7, slot = i0 >> 3;
  int bh   = xcd * 8 + (slot >> 4);
  int rb   = (slot & 15) * 64;
  int b    = bh >> 3;
  int tid  = threadIdx.x;
  int wid  = tid >> 6;            // 0..7
  int r16  = wid >> 1;            // row tile
  int half = wid & 1;             // mc half
  int l = tid & 63, l15 = l & 15, c = l >> 4;

  uint32_t dw = Dsw[bh * 512 + tid];
  Dl[tid] = dw;
  El[tid] = Esw[bh * 512 + tid];
  h2x2 dv2 = bits2h(dw);
  float mv = fmaxf((float)dv2[0], (float)dv2[1]);
  for (int m = 1; m < 64; m <<= 1) mv = fmaxf(mv, __shfl_xor(mv, m, 64));
  if (l == 0) redm[wid] = mv;
  __syncthreads();
  float Dmax = redm[0];
#pragma unroll
  for (int i = 1; i < 8; i++) Dmax = fmaxf(Dmax, redm[i]);
  float maxd = flog2(Dmax);

  int n = rb + r16 * 16 + l15;
  float svn = sp[bh * 1024 + n];
  float su  = svn + maxd;
  float ub  = fmaxf(su, 0.2f * su);      // >= true row max (leaky monotone)
  float cAf = fexp2(svn - ub + 8.0f);          // x256
  float cBf = fexp2(0.2f * svn - ub + 8.0f);   // x256
  h2x2 cA2; cA2[0] = (_Float16)cAf; cA2[1] = (_Float16)cAf;
  h2x2 cB2; cB2[0] = (_Float16)cBf; cB2[1] = (_Float16)cBf;
  const short* hpbase = hpbh + (size_t)bh * 32 * CT * 512;
  const uint32_t* atile = adjt + ((size_t)(b * 64 + (rb >> 4) + r16) * 32) * 128 + l * 2;

  f32x4 acc[CT];
#pragma unroll
  for (int i = 0; i < CT; i++) acc[i] = (f32x4){0.f, 0.f, 0.f, 0.f};
  f32x4 accp = (f32x4){0.f, 0.f, 0.f, 0.f};
  union { s16x8 s; f16x8 f; } ones;
#pragma unroll
  for (int j = 0; j < 8; j++) ones.s[j] = (short)0x3C00;   // fp16 1.0

  const int mcBeg = half * 16;
  u32x2 nam = *(const u32x2*)(atile + (size_t)mcBeg * 128);
  s16x8 nb[CT];
#pragma unroll
  for (int i = 0; i < CT; i++)
    nb[i] = *(const s16x8*)(hpbase + ((size_t)(mcBeg * CT + i) * 64 + l) * 8);
  u32x4 ndq = *(const u32x4*)&Dl[mcBeg * 16 + 4 * c];
  u32x4 neq = *(const u32x4*)&El[mcBeg * 16 + 4 * c];

#pragma unroll
  for (int t = 0; t < 16; ++t) {
    int mc = mcBeg + t;
    u32x2 am = nam;
    u32x4 dq = ndq, eq = neq;
    union { s16x8 s; f16x8 f; } cb[CT];
#pragma unroll
    for (int i = 0; i < CT; i++) cb[i].s = nb[i];
    if (t < 15) {
      int mcn = mc + 1;
      nam = *(const u32x2*)(atile + (size_t)mcn * 128);
#pragma unroll
      for (int i = 0; i < CT; i++)
        nb[i] = *(const s16x8*)(hpbase + ((size_t)(mcn * CT + i) * 64 + l) * 8);
      ndq = *(const u32x4*)&Dl[mcn * 16 + 4 * c];
      neq = *(const u32x4*)&El[mcn * 16 + 4 * c];
    }

    union { u32x4 w; s16x8 s; f16x8 f; } pu;
#pragma unroll
    for (int tt = 0; tt < 4; ++tt) {
      h2x2 p2 = __builtin_elementwise_max(cA2 * bits2h(dq[tt]), cB2 * bits2h(eq[tt]));
      uint32_t msk = __builtin_amdgcn_perm(0u, am[tt >> 1],
                                           (tt & 1) ? 0x03030202u : 0x01010000u);
      pu.w[tt] = h2bits(p2) & msk;
    }

#pragma unroll
    for (int i = 0; i < CT; i++)
      acc[i] = __builtin_amdgcn_mfma_f32_16x16x32_f16(pu.f, cb[i].f, acc[i], 0, 0, 0);
    accp = __builtin_amdgcn_mfma_f32_16x16x32_f16(pu.f, ones.f, accp, 0, 0, 0);
  }

  if (half == 1) {
#pragma unroll
    for (int i = 0; i < CT; i++)
#pragma unroll
      for (int r = 0; r < 4; r++) racc[r16][i * 4 + r][l] = acc[i][r];
#pragma unroll
    for (int r = 0; r < 4; r++) racc[r16][CT * 4 + r][l] = accp[r];
  }
  __syncthreads();
  if (half == 0) {
#pragma unroll
    for (int i = 0; i < CT; i++)
#pragma unroll
      for (int r = 0; r < 4; r++) acc[i][r] += racc[r16][i * 4 + r][l];
#pragma unroll
    for (int r = 0; r < 4; r++) {
      float rs  = accp[r] + racc[r16][CT * 4 + r][l];
      float inv = frcp(rs);
      int rown  = rb + r16 * 16 + 4 * c + r;
#pragma unroll
      for (int i = 0; i < CT; i++) {
        float v = acc[i][r] * inv;
        int col = i * 16 + l15;
        int h   = bh & 7;
        if (IS_L0) {
          v += bias[col];
          v = v > 0.f ? v : fexp2(v * LOG2E) - 1.f;   // elu
          size_t idx = ((size_t)(b * 1024 + rown)) * 256 + h * 32 + col;
          short vh = f2h(v);
          ((short*)outh)[idx] = vh;
          ((short*)outl)[idx] = f2h(v - h2f(vh));
        } else {
          ((float*)outh)[(((size_t)(b * 8 + h)) * 1024 + rown) * 16 + col] = v;
        }
      }
    }
  }
}

// ---------------------------------------------------------------------------
// Kernel F: mean over heads + bias + log_softmax(16)
// ---------------------------------------------------------------------------
__global__ __launch_bounds__(256) void k_final(
    const float* __restrict__ out1, const float* __restrict__ b1,
    float* __restrict__ out)
{
  int idx = blockIdx.x * 256 + threadIdx.x;
  if (idx >= 8192) return;
  int b = idx >> 10, n = idx & 1023;
  float v[16];
#pragma unroll
  for (int o = 0; o < 16; o++) v[o] = 0.f;
  for (int h = 0; h < 8; h++) {
    const float* p = out1 + (((size_t)(b * 8 + h)) * 1024 + n) * 16;
#pragma unroll
    for (int o = 0; o < 16; o++) v[o] += p[o];
  }
  float mx = -1e30f;
#pragma unroll
  for (int o = 0; o < 16; o++) {
    v[o] = v[o] * 0.125f + b1[o];
    mx = fmaxf(mx, v[o]);
  }
  float s = 0.f;
#pragma unroll
  for (int o = 0; o < 16; o++) s += fexp2((v[o] - mx) * LOG2E);
  float lse = flog2(s) * LN2;
#pragma unroll
  for (int o = 0; o < 16; o++) out[(size_t)idx * 16 + o] = v[o] - mx - lse;
}

// ---------------------------------------------------------------------------
extern "C" void kernel_launch(void* const* d_in, const int* in_sizes, int n_in,
                              void* d_out, int out_size, void* d_ws, size_t ws_size,
                              hipStream_t stream) {
  const float*   x     = (const float*)d_in[0];
  const int*     verts = (const int*)d_in[1];
  const void*    adj   = (const void*)d_in[2];   // int32 or uint8 — auto-detected
  const float*   emb   = (const float*)d_in[3];
  const float*   w0    = (const float*)d_in[4];
  const float*   as0   = (const float*)d_in[5];
  const float*   ad0   = (const float*)d_in[6];
  const float*   b0    = (const float*)d_in[7];
  const float*   w1    = (const float*)d_in[8];
  const float*   as1   = (const float*)d_in[9];
  const float*   ad1   = (const float*)d_in[10];
  const float*   b1    = (const float*)d_in[11];

  char* ws = (char*)d_ws;
  const size_t MB = 1ull << 20;
  const size_t KB = 1024;
  short* hpb0h = (short*)(ws);                         // 4 MB (dead after attn0)
  float* out1  = (float*)(ws);                         // 4 MB (aliases hpb0h)
  short* x1h   = (short*)(ws + 4 * MB);                // 4 MB
  short* x1l   = (short*)(ws + 8 * MB);                // 4 MB
  short* hpb1h = (short*)(ws + 12 * MB);               // 2 MB
  uint32_t* adjt = (uint32_t*)(ws + 14 * MB);          // 8 MB
  float* s0    = (float*)(ws + 22 * MB);               // 256 KB
  float* s1    = (float*)(ws + 22 * MB + 256 * KB);    // 256 KB
  short* wf0h  = (short*)(ws + 22 * MB + 512 * KB);    // 64 KB each
  short* wf0l  = (short*)(ws + 22 * MB + 576 * KB);
  short* wf1h  = (short*)(ws + 22 * MB + 640 * KB);
  short* wf1l  = (short*)(ws + 22 * MB + 704 * KB);
  uint32_t* Dsw0 = (uint32_t*)(ws + 22 * MB + 768 * KB);   // 128 KB each
  uint32_t* Esw0 = (uint32_t*)(ws + 22 * MB + 896 * KB);
  uint32_t* Dsw1 = (uint32_t*)(ws + 23 * MB);
  uint32_t* Esw1 = (uint32_t*)(ws + 23 * MB + 128 * KB);
  float* out   = (float*)d_out;

  k_megaprep<<<288, 256, 0, stream>>>(adj, adjt, w0, w1, wf0h, wf0l, wf1h, wf1l);
  k_hprime<128, 32, true><<<512, 256, 0, stream>>>(nullptr, nullptr, x, verts, emb,
                                             wf0h, wf0l, as0, ad0,
                                             hpb0h, s0, Dsw0, Esw0);
  k_attn<2, true><<<1024, 512, 0, stream>>>(s0, Dsw0, Esw0, hpb0h, adjt,
                                            b0, (void*)x1h, (void*)x1l);
  k_hprime<256, 16, false><<<512, 256, 0, stream>>>(x1h, x1l, nullptr, nullptr, nullptr,
                                             wf1h, wf1l, as1, ad1,
                                             hpb1h, s1, Dsw1, Esw1);
  k_attn<1, false><<<1024, 512, 0, stream>>>(s1, Dsw1, Esw1, hpb1h, adjt,
                                             b1, (void*)out1, nullptr);
  k_final<<<32, 256, 0, stream>>>(out1, b1, out);
}